// Round 1
// baseline (653.666 us; speedup 1.0000x reference)
//
#include <hip/hip_runtime.h>

// ---------------------------------------------------------------------------
// CrossAttention: out = mean_h softmax(softmax((x@Wq)/4 · K^T + v) * exp(cur))
// B=4096, IN=1024, H=16, E=256, N_EP=2048.
// Strategy: bf16 hi/lo split (3-pass MFMA) for fp32-class accuracy.
// ---------------------------------------------------------------------------

typedef __attribute__((ext_vector_type(8))) short bf16x8;
typedef __attribute__((ext_vector_type(4))) float f32x4;

typedef const __attribute__((address_space(1))) void* gcptr;
typedef __attribute__((address_space(3))) void* sptr;

__device__ __forceinline__ void gload16(const void* g, void* l) {
  __builtin_amdgcn_global_load_lds((gcptr)g, (sptr)l, 16, 0, 0);
}

// round-to-nearest-even fp32 -> bf16 (bit-level, avoids header API drift)
__device__ __forceinline__ unsigned short f2bf(float f) {
  unsigned int u = __float_as_uint(f);
  unsigned int r = (u + 0x7fffu + ((u >> 16) & 1u)) >> 16;
  return (unsigned short)r;
}
__device__ __forceinline__ float bf2f(unsigned short s) {
  return __uint_as_float(((unsigned int)s) << 16);
}

// ------------------------- elementwise split (x, keys) ---------------------
__global__ void k_split(const float* __restrict__ src,
                        unsigned short* __restrict__ hi,
                        unsigned short* __restrict__ lo, int n4) {
  int i = blockIdx.x * blockDim.x + threadIdx.x;
  if (i >= n4) return;
  float4 v = reinterpret_cast<const float4*>(src)[i];
  ushort4 h, l;
  h.x = f2bf(v.x); l.x = f2bf(v.x - bf2f(h.x));
  h.y = f2bf(v.y); l.y = f2bf(v.y - bf2f(h.y));
  h.z = f2bf(v.z); l.z = f2bf(v.z - bf2f(h.z));
  h.w = f2bf(v.w); l.w = f2bf(v.w - bf2f(h.w));
  reinterpret_cast<ushort4*>(hi)[i] = h;
  reinterpret_cast<ushort4*>(lo)[i] = l;
}

// ---------------- transpose + split Wq [1024,4096] -> WqT [4096,1024] ------
// folds the 1/E^0.25 = 0.25 query scale into the weights
__global__ void k_twq(const float* __restrict__ W,
                      unsigned short* __restrict__ th,
                      unsigned short* __restrict__ tl) {
  __shared__ float t[64][65];
  int tx = threadIdx.x & 63, ty = threadIdx.x >> 6;
  int c0 = blockIdx.x * 64, r0 = blockIdx.y * 64;
#pragma unroll
  for (int i = 0; i < 64; i += 4)
    t[ty + i][tx] = W[(size_t)(r0 + ty + i) * 4096 + (c0 + tx)] * 0.25f;
  __syncthreads();
#pragma unroll
  for (int i = 0; i < 64; i += 4) {
    float v = t[tx][ty + i];
    unsigned short h = f2bf(v);
    unsigned short l = f2bf(v - bf2f(h));
    size_t o = (size_t)(c0 + ty + i) * 1024 + (r0 + tx);
    th[o] = h; tl[o] = l;
  }
}

// ------------------- GEMM1: q = x @ WqT', both [.,K] row-major -------------
// A = x [4096,1024], B = WqT [4096,1024], C = q [4096,4096] written as
// bf16 hi/lo (which is exactly the [65536,256] per-(b,h) row view).
__global__ __launch_bounds__(256) void k_gemm1(
    const unsigned short* __restrict__ Ah, const unsigned short* __restrict__ Al,
    const unsigned short* __restrict__ Bh, const unsigned short* __restrict__ Bl,
    unsigned short* __restrict__ Qh, unsigned short* __restrict__ Ql) {
  __shared__ unsigned short As[2][128][32];
  __shared__ unsigned short Bs[2][128][32];
  const int tid = threadIdx.x;
  const int w = tid >> 6, l = tid & 63;
  const int lr = l & 15, lg = l >> 4;
  const int m0 = blockIdx.y * 128, n0 = blockIdx.x * 128;
  const int wr = (w >> 1) * 64, wc = (w & 1) * 64;
  const int srow = tid >> 2;           // staging row (16B/lane, 4 lanes/row)
  const int skel = (tid & 3) * 8;      // staging k element offset
  f32x4 acc[4][4] = {};

  const size_t gaBase = (size_t)(m0 + srow) * 1024 + skel;
  const size_t gbBase = (size_t)(n0 + srow) * 1024 + skel;
  char* lA0 = (char*)&As[0][0][0] + w * 1024;
  char* lA1 = (char*)&As[1][0][0] + w * 1024;
  char* lB0 = (char*)&Bs[0][0][0] + w * 1024;
  char* lB1 = (char*)&Bs[1][0][0] + w * 1024;

  for (int k0 = 0; k0 < 1024; k0 += 32) {
    gload16(Ah + gaBase + k0,             lA0);
    gload16(Ah + gaBase + 64 * 1024 + k0, lA0 + 4096);
    gload16(Al + gaBase + k0,             lA1);
    gload16(Al + gaBase + 64 * 1024 + k0, lA1 + 4096);
    gload16(Bh + gbBase + k0,             lB0);
    gload16(Bh + gbBase + 64 * 1024 + k0, lB0 + 4096);
    gload16(Bl + gbBase + k0,             lB1);
    gload16(Bl + gbBase + 64 * 1024 + k0, lB1 + 4096);
    __syncthreads();
    bf16x8 ah[4], am[4], bh[4], bm[4];
#pragma unroll
    for (int i = 0; i < 4; ++i) {
      ah[i] = *reinterpret_cast<const bf16x8*>(&As[0][wr + i * 16 + lr][lg * 8]);
      am[i] = *reinterpret_cast<const bf16x8*>(&As[1][wr + i * 16 + lr][lg * 8]);
      bh[i] = *reinterpret_cast<const bf16x8*>(&Bs[0][wc + i * 16 + lr][lg * 8]);
      bm[i] = *reinterpret_cast<const bf16x8*>(&Bs[1][wc + i * 16 + lr][lg * 8]);
    }
#pragma unroll
    for (int i = 0; i < 4; ++i)
#pragma unroll
      for (int j = 0; j < 4; ++j) {
        acc[i][j] = __builtin_amdgcn_mfma_f32_16x16x32_bf16(ah[i], bh[j], acc[i][j], 0, 0, 0);
        acc[i][j] = __builtin_amdgcn_mfma_f32_16x16x32_bf16(am[i], bh[j], acc[i][j], 0, 0, 0);
        acc[i][j] = __builtin_amdgcn_mfma_f32_16x16x32_bf16(ah[i], bm[j], acc[i][j], 0, 0, 0);
      }
    __syncthreads();
  }
  // epilogue: split q into bf16 hi/lo
#pragma unroll
  for (int i = 0; i < 4; ++i)
#pragma unroll
    for (int j = 0; j < 4; ++j)
#pragma unroll
      for (int r = 0; r < 4; ++r) {
        int row = m0 + wr + i * 16 + lg * 4 + r;
        int col = n0 + wc + j * 16 + lr;
        float v = acc[i][j][r];
        unsigned short hh = f2bf(v);
        unsigned short ll = f2bf(v - bf2f(hh));
        size_t o = (size_t)row * 4096 + col;
        Qh[o] = hh; Ql[o] = ll;
      }
}

// ---- fused GEMM2 + double softmax + head-mean ------------------------------
// block: 512 thr (8 waves), 32 q2-rows (= 2 b's x 16 heads), full N=2048.
// wave w owns n-slice [w*256, w*256+256); acc[2 mframes][16 nfrags] f32x4.
__global__ __launch_bounds__(512) void k_attn(
    const unsigned short* __restrict__ Qh, const unsigned short* __restrict__ Ql,
    const unsigned short* __restrict__ Kh, const unsigned short* __restrict__ Kl,
    const float* __restrict__ values, const float* __restrict__ cur,
    float* __restrict__ out) {
  __shared__ unsigned short Asm[2][32][256];  // q rows hi/lo, 32 KiB
  __shared__ float red[8][32];
  const int tid = threadIdx.x;
  const int w = tid >> 6, l = tid & 63;
  const int lr = l & 15, lg = l >> 4;
  const int r0 = blockIdx.x * 32;   // q2 row base
  const int n0 = w * 256;           // wave n-slice

  {  // stage 32x256 q rows (hi+lo) via global_load_lds, linear layout
    const size_t base = (size_t)r0 * 256 + (size_t)tid * 8;
    char* d0 = (char*)&Asm[0][0][0] + w * 1024;
    char* d1 = (char*)&Asm[1][0][0] + w * 1024;
    gload16(Qh + base,        d0);
    gload16(Qh + base + 4096, d0 + 8192);
    gload16(Ql + base,        d1);
    gload16(Ql + base + 4096, d1 + 8192);
  }
  __syncthreads();

  f32x4 acc[2][16] = {};
  for (int k0 = 0; k0 < 256; k0 += 32) {
    bf16x8 ah[2], am[2];
#pragma unroll
    for (int mf = 0; mf < 2; ++mf) {
      ah[mf] = *reinterpret_cast<const bf16x8*>(&Asm[0][mf * 16 + lr][k0 + lg * 8]);
      am[mf] = *reinterpret_cast<const bf16x8*>(&Asm[1][mf * 16 + lr][k0 + lg * 8]);
    }
#pragma unroll
    for (int j = 0; j < 16; ++j) {
      const size_t ko = (size_t)(n0 + j * 16 + lr) * 256 + k0 + lg * 8;
      bf16x8 bh = *reinterpret_cast<const bf16x8*>(Kh + ko);
      bf16x8 bm = *reinterpret_cast<const bf16x8*>(Kl + ko);
#pragma unroll
      for (int mf = 0; mf < 2; ++mf) {
        acc[mf][j] = __builtin_amdgcn_mfma_f32_16x16x32_bf16(ah[mf], bh, acc[mf][j], 0, 0, 0);
        acc[mf][j] = __builtin_amdgcn_mfma_f32_16x16x32_bf16(am[mf], bh, acc[mf][j], 0, 0, 0);
        acc[mf][j] = __builtin_amdgcn_mfma_f32_16x16x32_bf16(ah[mf], bm, acc[mf][j], 0, 0, 0);
      }
    }
  }

  // logits = acc + values[n]
#pragma unroll
  for (int j = 0; j < 16; ++j) {
    float vv = values[n0 + j * 16 + lr];
#pragma unroll
    for (int mf = 0; mf < 2; ++mf)
#pragma unroll
      for (int r = 0; r < 4; ++r) acc[mf][j][r] += vv;
  }

  const int rb = lg * 4;  // this lane's row base inside a 16-row frag
  // ---------------- first softmax: row max ----------------
  float M1[2][4];
#pragma unroll
  for (int mf = 0; mf < 2; ++mf)
#pragma unroll
    for (int r = 0; r < 4; ++r) {
      float m = acc[mf][0][r];
#pragma unroll
      for (int j = 1; j < 16; ++j) m = fmaxf(m, acc[mf][j][r]);
      m = fmaxf(m, __shfl_xor(m, 1));
      m = fmaxf(m, __shfl_xor(m, 2));
      m = fmaxf(m, __shfl_xor(m, 4));
      m = fmaxf(m, __shfl_xor(m, 8));
      M1[mf][r] = m;
    }
  if (lr == 0) {
#pragma unroll
    for (int mf = 0; mf < 2; ++mf)
#pragma unroll
      for (int r = 0; r < 4; ++r) red[w][mf * 16 + rb + r] = M1[mf][r];
  }
  __syncthreads();
#pragma unroll
  for (int mf = 0; mf < 2; ++mf)
#pragma unroll
    for (int r = 0; r < 4; ++r) {
      float m = red[0][mf * 16 + rb + r];
#pragma unroll
      for (int w2 = 1; w2 < 8; ++w2) m = fmaxf(m, red[w2][mf * 16 + rb + r]);
      M1[mf][r] = m;
    }
  __syncthreads();
  // ---------------- e1 = exp(l - M1), Z1 ----------------
  float Z1[2][4];
#pragma unroll
  for (int mf = 0; mf < 2; ++mf)
#pragma unroll
    for (int r = 0; r < 4; ++r) {
      float z = 0.f;
#pragma unroll
      for (int j = 0; j < 16; ++j) {
        float e = __expf(acc[mf][j][r] - M1[mf][r]);
        acc[mf][j][r] = e;
        z += e;
      }
      z += __shfl_xor(z, 1); z += __shfl_xor(z, 2);
      z += __shfl_xor(z, 4); z += __shfl_xor(z, 8);
      Z1[mf][r] = z;
    }
  if (lr == 0) {
#pragma unroll
    for (int mf = 0; mf < 2; ++mf)
#pragma unroll
      for (int r = 0; r < 4; ++r) red[w][mf * 16 + rb + r] = Z1[mf][r];
  }
  __syncthreads();
#pragma unroll
  for (int mf = 0; mf < 2; ++mf)
#pragma unroll
    for (int r = 0; r < 4; ++r) {
      float z = 0.f;
#pragma unroll
      for (int w2 = 0; w2 < 8; ++w2) z += red[w2][mf * 16 + rb + r];
      Z1[mf][r] = z;
    }
  __syncthreads();
  // ---------------- second softmax ----------------
  // logits2 = c*e1/Z1, max(logits2) = c/Z1 exactly (max e1 == 1)
  const float c0 = __expf(cur[(r0 >> 4) + 0]);
  const float c1 = __expf(cur[(r0 >> 4) + 1]);
  float Z2[2][4];
#pragma unroll
  for (int mf = 0; mf < 2; ++mf)
#pragma unroll
    for (int r = 0; r < 4; ++r) {
      float s2 = (mf ? c1 : c0) / Z1[mf][r];
      float z = 0.f;
#pragma unroll
      for (int j = 0; j < 16; ++j) {
        float o = __expf(s2 * (acc[mf][j][r] - 1.0f));
        acc[mf][j][r] = o;
        z += o;
      }
      z += __shfl_xor(z, 1); z += __shfl_xor(z, 2);
      z += __shfl_xor(z, 4); z += __shfl_xor(z, 8);
      Z2[mf][r] = z;
    }
  if (lr == 0) {
#pragma unroll
    for (int mf = 0; mf < 2; ++mf)
#pragma unroll
      for (int r = 0; r < 4; ++r) red[w][mf * 16 + rb + r] = Z2[mf][r];
  }
  __syncthreads();
#pragma unroll
  for (int mf = 0; mf < 2; ++mf)
#pragma unroll
    for (int r = 0; r < 4; ++r) {
      float z = 0.f;
#pragma unroll
      for (int w2 = 0; w2 < 8; ++w2) z += red[w2][mf * 16 + rb + r];
      Z2[mf][r] = z;
    }
  // ---------------- head-mean + write ----------------
  float rz[2][4];
#pragma unroll
  for (int mf = 0; mf < 2; ++mf)
#pragma unroll
    for (int r = 0; r < 4; ++r) rz[mf][r] = 1.0f / (16.0f * Z2[mf][r]);
#pragma unroll
  for (int mf = 0; mf < 2; ++mf)
#pragma unroll
    for (int j = 0; j < 16; ++j) {
      float s = acc[mf][j][0] * rz[mf][0] + acc[mf][j][1] * rz[mf][1] +
                acc[mf][j][2] * rz[mf][2] + acc[mf][j][3] * rz[mf][3];
      s += __shfl_xor(s, 16);
      s += __shfl_xor(s, 32);
      if (l < 16)
        out[(size_t)((r0 >> 4) + mf) * 2048 + n0 + j * 16 + l] = s;
    }
}

// ---------------------------------------------------------------------------
extern "C" void kernel_launch(void* const* d_in, const int* in_sizes, int n_in,
                              void* d_out, int out_size, void* d_ws, size_t ws_size,
                              hipStream_t stream) {
  const float* x    = (const float*)d_in[0];
  const float* cur  = (const float*)d_in[1];
  const float* Wq   = (const float*)d_in[2];
  const float* keys = (const float*)d_in[3];
  const float* vals = (const float*)d_in[4];
  float* out = (float*)d_out;

  char* ws = (char*)d_ws;
  unsigned short* x_hi = (unsigned short*)ws;  ws += (size_t)4096 * 1024 * 2;
  unsigned short* x_lo = (unsigned short*)ws;  ws += (size_t)4096 * 1024 * 2;
  unsigned short* w_hi = (unsigned short*)ws;  ws += (size_t)4096 * 1024 * 2;
  unsigned short* w_lo = (unsigned short*)ws;  ws += (size_t)4096 * 1024 * 2;
  unsigned short* k_hi = (unsigned short*)ws;  ws += (size_t)2048 * 256 * 2;
  unsigned short* k_lo = (unsigned short*)ws;  ws += (size_t)2048 * 256 * 2;
  unsigned short* q_hi = (unsigned short*)ws;  ws += (size_t)4096 * 4096 * 2;
  unsigned short* q_lo = (unsigned short*)ws;

  k_split<<<4096, 256, 0, stream>>>(x,    x_hi, x_lo, 4096 * 1024 / 4);
  k_split<<<512,  256, 0, stream>>>(keys, k_hi, k_lo, 2048 * 256 / 4);
  k_twq<<<dim3(64, 16), 256, 0, stream>>>(Wq, w_hi, w_lo);
  k_gemm1<<<dim3(32, 32), 256, 0, stream>>>(x_hi, x_lo, w_hi, w_lo, q_hi, q_lo);
  k_attn<<<2048, 512, 0, stream>>>(q_hi, q_lo, k_hi, k_lo, vals, cur, out);
}